// Round 8
// baseline (90.197 us; speedup 1.0000x reference)
//
#include <hip/hip_runtime.h>

// RecurrentFixed_PredPrey: 30 iterations of u = tanh(scalar * (drive + w ⊙ N4-stencil(u)))
// on 32768 independent 16x16 images. W_hidden is the fixed grid adjacency -> stencil.
//
// R7: R6 layout + image-pair packing (v_pk_*_f32) + packed Newton division (no v_rcp).
//   4 images/wave: lane = (g = l>>5 pair-slot, rg = (l>>4)&1 row-strip, c = l&15 column).
//   Lane owns rows {rg*8+k} of column c for images {4*wid' + 2g, +1} packed as float2.
//   horizontal: DPP row_shr:1/row_shl:1 per 32-bit half (16-lane DPP row == (g,rg) group,
//               bound_ctrl zeroes column edges free).
//   vertical:   rows in-register (packed adds); strip boundary rows 7<->8 via ONE
//               ds_bpermute per half (lane^16 publishes the row its partner needs).
// Activation per px-pair (9 pk + 2 exp + 2 bfi; NO v_rcp):
//   m = pk_fma(w, ns, drv)        [w, drv pre-scaled by K = 2*s*log2(e)]
//   e = exp2(-|m|) in (0,1]       [-|m| is a free source modifier]
//   d = 1 + e in (1,2];  r = 1/d via Newton: r0 = 16/17 - (8/17)e; 2x r = r*(2-d*r)
//   u = copysign(1 - 2*e*r, m)    [exp underflow -> u = +/-1 exactly]
// Phase structure (all ns, then all act) keeps 8 independent chains for ILP — R5's
// streamed variant serialized and died; this is the fix, with 2x the blocks.

namespace {

constexpr int HPIX   = 256;
constexpr int LAYERS = 30;
constexpr int WAVES_PER_BLOCK = 4;
constexpr int IMGS_PER_WAVE   = 4;   // 2 pair-slots x 2 packed

typedef float v2f __attribute__((ext_vector_type(2)));

template <int CTRL>
__device__ __forceinline__ float dppf(float x) {
    // old = 0, bound_ctrl=1: out-of-row source lanes yield 0.0f (image column edge)
    int r = __builtin_amdgcn_update_dpp(0, __float_as_int(x), CTRL, 0xF, 0xF, true);
    return __int_as_float(r);
}

__device__ __forceinline__ v2f act(v2f ns, v2f drv, v2f wc) {
    const v2f m = wc * ns + drv;                       // pk_fma
    v2f e;
    e.x = __builtin_amdgcn_exp2f(-__builtin_fabsf(m.x));   // -|m| = src modifier
    e.y = __builtin_amdgcn_exp2f(-__builtin_fabsf(m.y));
    const v2f d = e + 1.0f;                            // pk_add, d in (1,2]
    v2f r = e * (-8.0f / 17.0f) + (16.0f / 17.0f);     // pk_fma (seed, d-add folded)
    r = r * (2.0f - d * r);                            // pk_fma + pk_mul
    r = r * (2.0f - d * r);                            // rel err 1.2e-5
    const v2f t = 1.0f - 2.0f * (e * r);               // pk_mul + pk_fma
    v2f u;
    u.x = __builtin_copysignf(t.x, m.x);               // v_bfi_b32
    u.y = __builtin_copysignf(t.y, m.y);
    return u;
}

__global__ __launch_bounds__(WAVES_PER_BLOCK * 64)
void pp_kernel(const float* __restrict__ X, const float* __restrict__ pred,
               const float* __restrict__ w, const float* __restrict__ av,
               const float* __restrict__ bias, const float* __restrict__ scalar,
               float* __restrict__ out, int nb)
{
    const int lane = threadIdx.x & 63;
    const int wid  = blockIdx.x * WAVES_PER_BLOCK + (threadIdx.x >> 6);
    const int g    = lane >> 5;                 // pair slot 0..1
    const int rg   = (lane >> 4) & 1;           // row strip: 0 -> rows 0..7, 1 -> 8..15
    const int c    = lane & 15;                 // column 0..15
    const int imgA = wid * IMGS_PER_WAVE + g * 2;
    const bool actA = (imgA < nb);
    const bool actB = (imgA + 1 < nb);
    const int iA = actA ? imgA : 0;             // clamp for safe loads
    const int iB = actB ? imgA + 1 : 0;
    const int r0 = rg * 8;                      // first row of this lane's strip
    const size_t baseA = (size_t)iA * HPIX + r0 * 16 + c;
    const size_t baseB = (size_t)iB * HPIX + r0 * 16 + c;

    const float s = scalar[0];
    const float K = 2.0f * s * 1.4426950408889634f;   // 2*s*log2(e)

    v2f u[8], drv[8];
#pragma unroll
    for (int k = 0; k < 8; ++k) {
        const int p = r0 * 16 + k * 16 + c;            // param index (row r0+k, col c)
        const float pa = pred[baseA + k * 16];
        const float pb = pred[baseB + k * 16];
        const float xa = X[baseA + k * 16];
        const float xb = X[baseB + k * 16];
        const float bk = bias[p];
        const float ak = av[p];
        const float fa = (pa == -1.0f) ? 0.0f : pa;    // u_fix
        const float fb = (pb == -1.0f) ? 0.0f : pb;
        drv[k].x = K * ((fa + bk) + ak * xa);          // K-prescaled drive
        drv[k].y = K * ((fb + bk) + ak * xb);
        u[k].x = pa;                                   // scan carry = raw pred
        u[k].y = pb;
    }
    // weights for this column: image row-edge rows (0/15) vs middle rows (same both imgs)
    const float wEnd = K * w[c];          // row 0 (== row 15 by symmetry), col c
    const float wMid = K * w[16 + c];     // middle rows, col c
    const float wk0s = rg ? wMid : wEnd;  // k=0 is image row 0 only when rg==0
    const float wk7s = rg ? wEnd : wMid;  // k=7 is image row 15 only when rg==1
    const v2f w_k0 = {wk0s, wk0s};
    const v2f w_k7 = {wk7s, wk7s};
    const v2f w_md = {wMid, wMid};

    const int partner_addr = (lane ^ 16) << 2;   // ds_bpermute byte address (hoisted)
    const v2f vzero = {0.0f, 0.0f};

#pragma unroll 1
    for (int it = 0; it < LAYERS; ++it) {
        // strip-boundary exchange: publish the row the partner strip needs
        const v2f pub = rg ? u[0] : u[7];
        v2f nbr;
        nbr.x = __int_as_float(
            __builtin_amdgcn_ds_bpermute(partner_addr, __float_as_int(pub.x)));
        nbr.y = __int_as_float(
            __builtin_amdgcn_ds_bpermute(partner_addr, __float_as_int(pub.y)));
        const v2f tN = rg ? nbr : vzero;   // top neighbor of k=0 (0 at image top edge)
        const v2f bN = rg ? vzero : nbr;   // bottom neighbor of k=7 (0 at image bottom)

        // vertical neighbor sums (packed; all old-u reads before any update)
        v2f ns[8];
        ns[0] = tN + u[1];
        ns[7] = u[6] + bN;
#pragma unroll
        for (int k = 1; k < 7; ++k) ns[k] = u[k - 1] + u[k + 1];
        // horizontal via DPP on each 32-bit half (bound_ctrl zeroes column edges)
#pragma unroll
        for (int k = 0; k < 8; ++k) {
            ns[k].x += dppf<0x111>(u[k].x) + dppf<0x101>(u[k].x);
            ns[k].y += dppf<0x111>(u[k].y) + dppf<0x101>(u[k].y);
        }
        // activation (packed; 8 independent chains for ILP)
        u[0] = act(ns[0], drv[0], w_k0);
#pragma unroll
        for (int k = 1; k < 7; ++k) u[k] = act(ns[k], drv[k], w_md);
        u[7] = act(ns[7], drv[7], w_k7);
    }

#pragma unroll
    for (int k = 0; k < 8; ++k) {
        if (actA) out[baseA + k * 16] = u[k].x;
        if (actB) out[baseB + k * 16] = u[k].y;
    }
}

} // namespace

extern "C" void kernel_launch(void* const* d_in, const int* in_sizes, int n_in,
                              void* d_out, int out_size, void* d_ws, size_t ws_size,
                              hipStream_t stream) {
    // setup_inputs order: X, pred, W_hidden, w, a, bias, scalar
    const float* X      = (const float*)d_in[0];
    const float* pred   = (const float*)d_in[1];
    // d_in[2] = W_hidden: fixed grid adjacency, hardcoded as the stencil
    const float* w      = (const float*)d_in[3];
    const float* av     = (const float*)d_in[4];
    const float* bias   = (const float*)d_in[5];
    const float* scalar = (const float*)d_in[6];
    float* out = (float*)d_out;

    const int nb = in_sizes[0] / HPIX;  // batch rows (32768)
    const int imgs_per_block = WAVES_PER_BLOCK * IMGS_PER_WAVE;    // 16
    const int blocks = (nb + imgs_per_block - 1) / imgs_per_block; // 2048

    pp_kernel<<<dim3(blocks), dim3(WAVES_PER_BLOCK * 64), 0, stream>>>(
        X, pred, w, av, bias, scalar, out, nb);
}

// Round 9
// 82.098 us; speedup vs baseline: 1.0986x; 1.0986x over previous
//
#include <hip/hip_runtime.h>

// RecurrentFixed_PredPrey: 30 iterations of u = tanh(scalar * (drive + w ⊙ N4-stencil(u)))
// on 32768 independent 16x16 images. W_hidden is the fixed grid adjacency -> stencil.
//
// R8 = R6 layout (proven: 2 images/wave, 8 px/lane, scalar f32) + batch-8 reciprocal.
//   lane = (g = l>>5 image, rg = (l>>4)&1 row-strip, c = l&15 column)
//   lane owns rows {rg*8+k, k=0..7} of column c in registers u[0..7].
//   horizontal: DPP row_shr:1/row_shl:1 (16-lane DPP row == (g,rg) group; bound_ctrl
//               zeroes column edges free).
//   vertical:   rows in-register; strip boundary rows 7<->8 via ONE ds_bpermute
//               (each lane publishes the row its partner lane^16 needs).
// Activation via batch (Montgomery) inversion — ONE v_rcp per 8 pixels:
//   m = fma(w2, ns, drv2)            [w, drv pre-scaled by K = 2*s*log2(e)]
//   e = exp2(-|m|) in (0,1]          [-|m| = free exp2 source modifiers]
//   d = 1 + e in (1,2];  R_k = 1/d_k via prefix products + one rcp + back-recovery
//   tanh|x| = (1-e)/(1+e) = 2*R_k - 1  ->  u = copysign(fma(R_k, 2, -1), m)
// Per wave-layer: ~80 VALU + 8 exp2 + 1 rcp (vs R6's 51 VALU + 8 exp2 + 8 rcp).
// Accuracy: rcp 1ulp + ~20 rounded muls ~ 2e-6/step, well under the 0.02 threshold
// after 30-layer amplification (R7's 1.2e-5/step measured 0.0195 -> this ~0.008).

namespace {

constexpr int HPIX   = 256;
constexpr int LAYERS = 30;
constexpr int WAVES_PER_BLOCK = 4;
constexpr int IMGS_PER_WAVE   = 2;

template <int CTRL>
__device__ __forceinline__ float dppf(float x) {
    // old = 0, bound_ctrl=1: out-of-row source lanes yield 0.0f (image column edge)
    int r = __builtin_amdgcn_update_dpp(0, __float_as_int(x), CTRL, 0xF, 0xF, true);
    return __int_as_float(r);
}

__global__ __launch_bounds__(WAVES_PER_BLOCK * 64)
void pp_kernel(const float* __restrict__ X, const float* __restrict__ pred,
               const float* __restrict__ w, const float* __restrict__ av,
               const float* __restrict__ bias, const float* __restrict__ scalar,
               float* __restrict__ out, int nb)
{
    const int lane = threadIdx.x & 63;
    const int wid  = blockIdx.x * WAVES_PER_BLOCK + (threadIdx.x >> 6);
    const int g    = lane >> 5;                 // image in wave: 0..1
    const int rg   = (lane >> 4) & 1;           // row strip: 0 -> rows 0..7, 1 -> 8..15
    const int c    = lane & 15;                 // column 0..15
    const int img  = wid * IMGS_PER_WAVE + g;
    const bool active = (img < nb);
    const int imgc = active ? img : 0;          // clamp for safe loads
    const int r0   = rg * 8;                    // first row of this lane's strip
    const size_t base = (size_t)imgc * HPIX + r0 * 16 + c;   // pixel (r0, c)

    const float s = scalar[0];
    const float K = 2.0f * s * 1.4426950408889634f;   // 2*s*log2(e)

    float u[8], drv[8];
#pragma unroll
    for (int k = 0; k < 8; ++k) {
        const int p = r0 * 16 + k * 16 + c;            // param index (row r0+k, col c)
        const float pr = pred[base + k * 16];
        const float x  = X[base + k * 16];
        const float fu = (pr == -1.0f) ? 0.0f : pr;    // u_fix
        drv[k] = K * ((fu + bias[p]) + av[p] * x);     // K-prescaled layer-invariant drive
        u[k]   = pr;                                   // scan carry = raw pred
    }
    // weights for this column: image row-edge rows (0/15) vs middle rows.
    // w[row0,c] == w[row15,c] by edge/corner symmetry.
    const float wEnd = K * w[c];          // row 0 (== row 15), col c
    const float wMid = K * w[16 + c];     // middle rows, col c
    const float w_k0 = rg ? wMid : wEnd;  // k=0 is image row 0 only when rg==0
    const float w_k7 = rg ? wEnd : wMid;  // k=7 is image row 15 only when rg==1

    const int partner_addr = (lane ^ 16) << 2;   // ds_bpermute byte address (hoisted)

#pragma unroll 1
    for (int it = 0; it < LAYERS; ++it) {
        // strip-boundary exchange: publish the row the partner strip needs
        // (rg0 partner needs our row7=u[7]; rg1 partner needs our row8=u[0])
        const float pub = rg ? u[0] : u[7];
        const float nbr = __int_as_float(
            __builtin_amdgcn_ds_bpermute(partner_addr, __float_as_int(pub)));
        const float tN = rg ? nbr : 0.0f;   // top neighbor of k=0 (0 at image top edge)
        const float bN = rg ? 0.0f : nbr;   // bottom neighbor of k=7 (0 at image bottom)

        // vertical neighbor sums (all old-u reads happen before any u update)
        float ns[8];
        ns[0] = tN + u[1];
        ns[7] = u[6] + bN;
#pragma unroll
        for (int k = 1; k < 7; ++k) ns[k] = u[k - 1] + u[k + 1];
        // horizontal via DPP (bound_ctrl zeroes column edges)
#pragma unroll
        for (int k = 0; k < 8; ++k)
            ns[k] = ns[k] + dppf<0x111>(u[k]) + dppf<0x101>(u[k]);

        // activation phase 1: m, e = exp2(-|m|), d = 1+e, prefix products
        float m[8], d[8], P[8];
#pragma unroll
        for (int k = 0; k < 8; ++k) {
            const float wc = (k == 0) ? w_k0 : (k == 7) ? w_k7 : wMid;
            m[k] = __builtin_fmaf(wc, ns[k], drv[k]);
            const float e = __builtin_amdgcn_exp2f(-__builtin_fabsf(m[k]));
            d[k] = e + 1.0f;                           // in (1, 2]
        }
        P[0] = d[0];
#pragma unroll
        for (int k = 1; k < 8; ++k) P[k] = P[k - 1] * d[k];   // P[7] <= 256

        // ONE reciprocal for all 8 divisions, then back-recovery:
        float R = __builtin_amdgcn_rcpf(P[7]);
#pragma unroll
        for (int k = 7; k >= 1; --k) {
            const float invk = R * P[k - 1];           // 1/d[k]
            R = R * d[k];                              // 1/(d[0]..d[k-1])
            u[k] = __builtin_copysignf(__builtin_fmaf(invk, 2.0f, -1.0f), m[k]);
        }
        u[0] = __builtin_copysignf(__builtin_fmaf(R, 2.0f, -1.0f), m[0]);
    }

    if (active) {
#pragma unroll
        for (int k = 0; k < 8; ++k)
            out[base + k * 16] = u[k];
    }
}

} // namespace

extern "C" void kernel_launch(void* const* d_in, const int* in_sizes, int n_in,
                              void* d_out, int out_size, void* d_ws, size_t ws_size,
                              hipStream_t stream) {
    // setup_inputs order: X, pred, W_hidden, w, a, bias, scalar
    const float* X      = (const float*)d_in[0];
    const float* pred   = (const float*)d_in[1];
    // d_in[2] = W_hidden: fixed grid adjacency, hardcoded as the stencil
    const float* w      = (const float*)d_in[3];
    const float* av     = (const float*)d_in[4];
    const float* bias   = (const float*)d_in[5];
    const float* scalar = (const float*)d_in[6];
    float* out = (float*)d_out;

    const int nb = in_sizes[0] / HPIX;  // batch rows (32768)
    const int imgs_per_block = WAVES_PER_BLOCK * IMGS_PER_WAVE;    // 8
    const int blocks = (nb + imgs_per_block - 1) / imgs_per_block; // 4096

    pp_kernel<<<dim3(blocks), dim3(WAVES_PER_BLOCK * 64), 0, stream>>>(
        X, pred, w, av, bias, scalar, out, nb);
}

// Round 10
// 79.061 us; speedup vs baseline: 1.1409x; 1.0384x over previous
//
#include <hip/hip_runtime.h>

// RecurrentFixed_PredPrey: 30 iterations of u = tanh(scalar * (drive + w ⊙ N4-stencil(u)))
// on 32768 independent 16x16 images. W_hidden is the fixed grid adjacency -> stencil.
//
// R9 = R6 layout (proven: 2 images/wave, 8 px/lane, scalar f32) + batch-2 reciprocal.
//   lane = (g = l>>5 image, rg = (l>>4)&1 row-strip, c = l&15 column)
//   lane owns rows {rg*8+k, k=0..7} of column c in registers u[0..7].
//   horizontal: DPP row_shr:1/row_shl:1 (16-lane DPP row == (g,rg) group; bound_ctrl
//               zeroes column edges free).
//   vertical:   rows in-register; strip boundary rows 7<->8 via ONE ds_bpermute
//               (each lane publishes the row its partner lane^16 needs).
// Activation: m = fma(w2, ns, drv2) [K-prescaled], e = exp2(-|m|), d = 1+e in (1,2],
//   tanh|x| = 2/(1+e) - 1  ->  u = copysign(fma(inv, 2, -1), m).
// Batch-2 inversion (cycle model: trans ~16.5 cyc issue, VALU 2 cyc -> rcp is the wall):
//   per pair {d0,d1}: P = d0*d1; R = rcp(P); inv0 = R*d1; inv1 = R*d0
//   -> 1 rcp + 3 mul (22.5 cyc) replaces 2 rcp (33 cyc); 4 independent pairs keep ILP.
//   (R8's batch-8 lost to serial chains/array bloat; batch-2 is the minimal form.)
// Accuracy: rcp 1ulp + 2 muls ~ 1.8e-7/step -> absmax ~0.004-0.006 (threshold 0.02).

namespace {

constexpr int HPIX   = 256;
constexpr int LAYERS = 30;
constexpr int WAVES_PER_BLOCK = 4;
constexpr int IMGS_PER_WAVE   = 2;

template <int CTRL>
__device__ __forceinline__ float dppf(float x) {
    // old = 0, bound_ctrl=1: out-of-row source lanes yield 0.0f (image column edge)
    int r = __builtin_amdgcn_update_dpp(0, __float_as_int(x), CTRL, 0xF, 0xF, true);
    return __int_as_float(r);
}

__global__ __launch_bounds__(WAVES_PER_BLOCK * 64)
void pp_kernel(const float* __restrict__ X, const float* __restrict__ pred,
               const float* __restrict__ w, const float* __restrict__ av,
               const float* __restrict__ bias, const float* __restrict__ scalar,
               float* __restrict__ out, int nb)
{
    const int lane = threadIdx.x & 63;
    const int wid  = blockIdx.x * WAVES_PER_BLOCK + (threadIdx.x >> 6);
    const int g    = lane >> 5;                 // image in wave: 0..1
    const int rg   = (lane >> 4) & 1;           // row strip: 0 -> rows 0..7, 1 -> 8..15
    const int c    = lane & 15;                 // column 0..15
    const int img  = wid * IMGS_PER_WAVE + g;
    const bool active = (img < nb);
    const int imgc = active ? img : 0;          // clamp for safe loads
    const int r0   = rg * 8;                    // first row of this lane's strip
    const size_t base = (size_t)imgc * HPIX + r0 * 16 + c;   // pixel (r0, c)

    const float s = scalar[0];
    const float K = 2.0f * s * 1.4426950408889634f;   // 2*s*log2(e)

    float u[8], drv[8];
#pragma unroll
    for (int k = 0; k < 8; ++k) {
        const int p = r0 * 16 + k * 16 + c;            // param index (row r0+k, col c)
        const float pr = pred[base + k * 16];
        const float x  = X[base + k * 16];
        const float fu = (pr == -1.0f) ? 0.0f : pr;    // u_fix
        drv[k] = K * ((fu + bias[p]) + av[p] * x);     // K-prescaled layer-invariant drive
        u[k]   = pr;                                   // scan carry = raw pred
    }
    // weights for this column: image row-edge rows (0/15) vs middle rows.
    // w[row0,c] == w[row15,c] by edge/corner symmetry.
    const float wEnd = K * w[c];          // row 0 (== row 15), col c
    const float wMid = K * w[16 + c];     // middle rows, col c
    const float w_k0 = rg ? wMid : wEnd;  // k=0 is image row 0 only when rg==0
    const float w_k7 = rg ? wEnd : wMid;  // k=7 is image row 15 only when rg==1

    const int partner_addr = (lane ^ 16) << 2;   // ds_bpermute byte address (hoisted)

#pragma unroll 1
    for (int it = 0; it < LAYERS; ++it) {
        // strip-boundary exchange: publish the row the partner strip needs
        // (rg0 partner needs our row7=u[7]; rg1 partner needs our row8=u[0])
        const float pub = rg ? u[0] : u[7];
        const float nbr = __int_as_float(
            __builtin_amdgcn_ds_bpermute(partner_addr, __float_as_int(pub)));
        const float tN = rg ? nbr : 0.0f;   // top neighbor of k=0 (0 at image top edge)
        const float bN = rg ? 0.0f : nbr;   // bottom neighbor of k=7 (0 at image bottom)

        // vertical neighbor sums (all old-u reads happen before any u update)
        float ns[8];
        ns[0] = tN + u[1];
        ns[7] = u[6] + bN;
#pragma unroll
        for (int k = 1; k < 7; ++k) ns[k] = u[k - 1] + u[k + 1];
        // horizontal via DPP (bound_ctrl zeroes column edges)
#pragma unroll
        for (int k = 0; k < 8; ++k)
            ns[k] = ns[k] + dppf<0x111>(u[k]) + dppf<0x101>(u[k]);

        // activation phase 1: m, d = 1 + exp2(-|m|) per pixel (8 independent chains)
        float m[8], dd[8];
#pragma unroll
        for (int k = 0; k < 8; ++k) {
            const float wc = (k == 0) ? w_k0 : (k == 7) ? w_k7 : wMid;
            m[k]  = __builtin_fmaf(wc, ns[k], drv[k]);
            dd[k] = __builtin_amdgcn_exp2f(-__builtin_fabsf(m[k])) + 1.0f;  // (1,2]
        }
        // activation phase 2: batch-2 reciprocal (one v_rcp per pixel-pair)
#pragma unroll
        for (int k = 0; k < 8; k += 2) {
            const float P  = dd[k] * dd[k + 1];
            const float R  = __builtin_amdgcn_rcpf(P);
            const float i0 = R * dd[k + 1];            // 1/dd[k]
            const float i1 = R * dd[k];                // 1/dd[k+1]
            u[k]     = __builtin_copysignf(__builtin_fmaf(i0, 2.0f, -1.0f), m[k]);
            u[k + 1] = __builtin_copysignf(__builtin_fmaf(i1, 2.0f, -1.0f), m[k + 1]);
        }
    }

    if (active) {
#pragma unroll
        for (int k = 0; k < 8; ++k)
            out[base + k * 16] = u[k];
    }
}

} // namespace

extern "C" void kernel_launch(void* const* d_in, const int* in_sizes, int n_in,
                              void* d_out, int out_size, void* d_ws, size_t ws_size,
                              hipStream_t stream) {
    // setup_inputs order: X, pred, W_hidden, w, a, bias, scalar
    const float* X      = (const float*)d_in[0];
    const float* pred   = (const float*)d_in[1];
    // d_in[2] = W_hidden: fixed grid adjacency, hardcoded as the stencil
    const float* w      = (const float*)d_in[3];
    const float* av     = (const float*)d_in[4];
    const float* bias   = (const float*)d_in[5];
    const float* scalar = (const float*)d_in[6];
    float* out = (float*)d_out;

    const int nb = in_sizes[0] / HPIX;  // batch rows (32768)
    const int imgs_per_block = WAVES_PER_BLOCK * IMGS_PER_WAVE;    // 8
    const int blocks = (nb + imgs_per_block - 1) / imgs_per_block; // 4096

    pp_kernel<<<dim3(blocks), dim3(WAVES_PER_BLOCK * 64), 0, stream>>>(
        X, pred, w, av, bias, scalar, out, nb);
}